// Round 11
// baseline (8187.093 us; speedup 1.0000x reference)
//
#include <hip/hip_runtime.h>
#include <hip/hip_bf16.h>

#define T_SEQ 512
#define HID   512
#define IND   128
#define HBUF  524288          // bytes per tagged h buffer: 256*512*4
#define TICKO (2 * HBUF)      // per-XCD ticket counters

typedef __attribute__((ext_vector_type(8))) short short8;
typedef __attribute__((ext_vector_type(4))) float f32x4;

static __device__ __forceinline__ unsigned short f2bf(float x) {
  __hip_bfloat16 h = __float2bfloat16(x);
  return __builtin_bit_cast(unsigned short, h);
}
static __device__ __forceinline__ float bf2f(unsigned short s) {
  unsigned u = ((unsigned)s) << 16;
  return __builtin_bit_cast(float, u);
}
static __device__ __forceinline__ float sigf(float x) {
  return 1.0f / (1.0f + __expf(-x));
}
static __device__ __forceinline__ float tanhfast(float x) {
  float e = __expf(2.0f * x);   // saturates cleanly, no inf/inf
  return 1.0f - 2.0f / (e + 1.0f);
}
static __device__ __forceinline__ unsigned long long ald(const unsigned long long* p) {
  return __hip_atomic_load(p, __ATOMIC_RELAXED, __HIP_MEMORY_SCOPE_AGENT);
}

__global__ __launch_bounds__(256, 1)
void lstm_persist(const float* __restrict__ x,
                  const float* __restrict__ w_ih,
                  const float* __restrict__ w_hh,
                  const float* __restrict__ b_ih,
                  const float* __restrict__ b_hh,
                  const float* __restrict__ w_lin,
                  const float* __restrict__ b_lin,
                  float* __restrict__ out,
                  unsigned char* __restrict__ ws)
{
  // LDS 128KB (forces exactly 1 WG/CU -> exactly 32 WGs per XCD):
  // [0,64K) w_hh staging (preamble only). [64K,128K) w_ih resident.
  __shared__ unsigned char lds[131072];
  __shared__ int slot_sh;

  const int tid  = threadIdx.x;
  const int wave = tid >> 6;
  const int lane = tid & 63;
  const int l15  = lane & 15;
  const int lq   = lane >> 4;

  // ---- runtime XCD-local group formation ----
  unsigned xcd;
  asm volatile("s_getreg_b32 %0, hwreg(HW_REG_XCC_ID)" : "=s"(xcd));
  if (tid == 0) {
    unsigned* tick = (unsigned*)(ws + TICKO) + (size_t)xcd * 32;  // 128B apart
    slot_sh = (int)__hip_atomic_fetch_add(tick, 1u, __ATOMIC_RELAXED,
                                          __HIP_MEMORY_SCOPE_AGENT);
  }
  __syncthreads();
  const int slot = slot_sh;
  if (slot >= 16) return;                 // 16 workers per XCD, rest exit
  const int grp = (int)xcd * 2 + (slot >> 3);   // 0..15, both groups same XCD
  const int ni  = slot & 7;                     // 0..7: WG's 64 h-col slice
  const int m16 = grp * 16;                     // group's batch rows
  const int n0  = ni * 64 + wave * 16;          // this wave's h-col base

  // ---- stage w_ih: 256 gate-rows (4 gates x 64 cols of this WG) x 128 k ----
  for (int it = 0; it < 16; ++it) {
    int idx  = it * 256 + tid;        // 0..4095
    int r    = idx >> 4;              // 0..255
    int c8   = idx & 15;
    int grow = (r >> 6) * HID + ni * 64 + (r & 63);
    const float* gp = w_ih + (size_t)grow * IND + c8 * 8;
    f32x4 a = *(const f32x4*)gp;
    f32x4 b = *(const f32x4*)(gp + 4);
    short8 s;
    s[0] = (short)f2bf(a[0]); s[1] = (short)f2bf(a[1]);
    s[2] = (short)f2bf(a[2]); s[3] = (short)f2bf(a[3]);
    s[4] = (short)f2bf(b[0]); s[5] = (short)f2bf(b[1]);
    s[6] = (short)f2bf(b[2]); s[7] = (short)f2bf(b[3]);
    int off = 65536 + r * 256 + ((c8 * 16) ^ ((r & 7) << 4));
    *(short8*)(lds + off) = s;
  }

  // ---- stage + gather w_hh in 4 rounds (round rd serves wave rd) ----
  short8 wf[64];
  for (int rd = 0; rd < 4; ++rd) {
    __syncthreads();                  // prior round's gather done before overwrite
    for (int it = 0; it < 16; ++it) {
      int idx  = it * 256 + tid;      // 0..4095
      int r    = idx >> 6;            // 0..63  (gate*16 + j)
      int c8   = idx & 63;
      int grow = (r >> 4) * HID + ni * 64 + rd * 16 + (r & 15);
      const float* gp = w_hh + (size_t)grow * HID + c8 * 8;
      f32x4 a = *(const f32x4*)gp;
      f32x4 b = *(const f32x4*)(gp + 4);
      short8 s;
      s[0] = (short)f2bf(a[0]); s[1] = (short)f2bf(a[1]);
      s[2] = (short)f2bf(a[2]); s[3] = (short)f2bf(a[3]);
      s[4] = (short)f2bf(b[0]); s[5] = (short)f2bf(b[1]);
      s[6] = (short)f2bf(b[2]); s[7] = (short)f2bf(b[3]);
      int off = r * 1024 + ((c8 * 16) ^ ((r & 7) << 4));
      *(short8*)(lds + off) = s;
    }
    __syncthreads();
    if (wave == rd) {
      // pin this wave's 64 B-fragments in regs: volatile (cannot rematerialize)
#pragma unroll
      for (int gg = 0; gg < 4; ++gg) {
#pragma unroll
        for (int ks = 0; ks < 16; ++ks) {
          int r   = gg * 16 + l15;
          int off = r * 1024 + (((ks * 64) + lq * 16) ^ ((r & 7) << 4));
          wf[gg * 16 + ks] = *(const volatile short8*)(lds + off);
        }
      }
    }
  }
  __syncthreads();   // protect staging until last gather done

  // bias per gate for this lane's column
  float biasv[4];
#pragma unroll
  for (int gg = 0; gg < 4; ++gg) {
    int gc = gg * HID + n0 + l15;
    biasv[gg] = b_ih[gc] + b_hh[gc];
  }

  // per-lane x base (bytes): row = m16 + l15, chunk lq*8 fp32
  const unsigned char* xbase = (const unsigned char*)x
      + (size_t)(m16 + l15) * T_SEQ * IND * 4 + (size_t)lq * 32;

  f32x4 cacc = {0.f, 0.f, 0.f, 0.f};

  // ---- x-projection (B-frags from LDS; dst = bias + x_t @ w_ih^T) ----
  auto xproj = [&](int t, f32x4* dst) {
    const float* xp = (const float*)(xbase + (size_t)t * IND * 4);
    short8 xa[4];
#pragma unroll
    for (int ks = 0; ks < 4; ++ks) {
      f32x4 a = *(const f32x4*)(xp + ks * 32);
      f32x4 b = *(const f32x4*)(xp + ks * 32 + 4);
      short8 s;
      s[0] = (short)f2bf(a[0]); s[1] = (short)f2bf(a[1]);
      s[2] = (short)f2bf(a[2]); s[3] = (short)f2bf(a[3]);
      s[4] = (short)f2bf(b[0]); s[5] = (short)f2bf(b[1]);
      s[6] = (short)f2bf(b[2]); s[7] = (short)f2bf(b[3]);
      xa[ks] = s;
    }
#pragma unroll
    for (int gg = 0; gg < 4; ++gg) {
      f32x4 v = {biasv[gg], biasv[gg], biasv[gg], biasv[gg]};
      dst[gg] = v;
    }
#pragma unroll
    for (int ks = 0; ks < 4; ++ks) {
#pragma unroll
      for (int gg = 0; gg < 4; ++gg) {
        int rr  = gg * 64 + wave * 16 + l15;
        int off = 65536 + rr * 256 + (((ks * 64) + lq * 16) ^ ((rr & 7) << 4));
        short8 bfr = *(const short8*)(lds + off);
        dst[gg] = __builtin_amdgcn_mfma_f32_16x16x32_bf16(xa[ks], bfr, dst[gg], 0, 0, 0);
      }
    }
  };

  f32x4 xacc[4];
  xproj(0, xacc);

  // lane's h-row base in ull units: dword (m16+l15)*512 + lq*8, /2
  const size_t rbase = (size_t)(m16 + l15) * 256 + (size_t)lq * 4;
  const int startp = (ni * 4 + wave) & 7;   // rotated slice order per wave

#pragma unroll 1
  for (int t = 0; t < T_SEQ; ++t) {
    f32x4 acc[4];
#pragma unroll
    for (int gg = 0; gg < 4; ++gg) acc[gg] = xacc[gg];

    if (t > 0) {
      const unsigned long long* bb =
          (const unsigned long long*)(ws + (size_t)(t & 1) * HBUF);
      const unsigned long long tp =
          (unsigned long long)(unsigned)t | ((unsigned long long)(unsigned)t << 32);
      // ---- slice-pipelined consume: per producer-slice p, poll->extract->MFMA
#pragma unroll 1
      for (int i = 0; i < 8; ++i) {
        int p = (startp + i) & 7;
        const unsigned long long* rp = bb + rbase + (size_t)p * 32;
        unsigned long long q0, q1, q2, q3, q4, q5, q6, q7;
        for (;;) {
          q0 = ald(rp);      q1 = ald(rp + 1);  q2 = ald(rp + 2);  q3 = ald(rp + 3);
          q4 = ald(rp + 16); q5 = ald(rp + 17); q6 = ald(rp + 18); q7 = ald(rp + 19);
          unsigned long long diff =
              ((q0 ^ tp) | (q1 ^ tp) | (q2 ^ tp) | (q3 ^ tp) |
               (q4 ^ tp) | (q5 ^ tp) | (q6 ^ tp) | (q7 ^ tp)) & 0x0000ffff0000ffffULL;
          if (__all(diff == 0)) break;
        }
        short8 a0, a1;
        a0[0] = (short)(q0 >> 16); a0[1] = (short)(q0 >> 48);
        a0[2] = (short)(q1 >> 16); a0[3] = (short)(q1 >> 48);
        a0[4] = (short)(q2 >> 16); a0[5] = (short)(q2 >> 48);
        a0[6] = (short)(q3 >> 16); a0[7] = (short)(q3 >> 48);
        a1[0] = (short)(q4 >> 16); a1[1] = (short)(q4 >> 48);
        a1[2] = (short)(q5 >> 16); a1[3] = (short)(q5 >> 48);
        a1[4] = (short)(q6 >> 16); a1[5] = (short)(q6 >> 48);
        a1[6] = (short)(q7 >> 16); a1[7] = (short)(q7 >> 48);
        const int ks0 = p * 2, ks1 = p * 2 + 1;
#pragma unroll
        for (int gg = 0; gg < 4; ++gg)
          acc[gg] = __builtin_amdgcn_mfma_f32_16x16x32_bf16(a0, wf[gg * 16 + ks0], acc[gg], 0, 0, 0);
#pragma unroll
        for (int gg = 0; gg < 4; ++gg)
          acc[gg] = __builtin_amdgcn_mfma_f32_16x16x32_bf16(a1, wf[gg * 16 + ks1], acc[gg], 0, 0, 0);
      }
    }

    // ---- pointwise LSTM cell (C/D layout: col=l15, row=lq*4+r) ----
    unsigned* hn = (unsigned*)(ws + (size_t)((t + 1) & 1) * HBUF);
    const unsigned tag = (unsigned)(t + 1);
#pragma unroll
    for (int r = 0; r < 4; ++r) {
      float iv = sigf(acc[0][r]);
      float fv = sigf(acc[1][r]);
      float gv = tanhfast(acc[2][r]);
      float ov = sigf(acc[3][r]);
      float cn = fv * cacc[r] + iv * gv;
      cacc[r] = cn;
      unsigned w = ((unsigned)f2bf(ov * tanhfast(cn)) << 16) | tag;
      int row = m16 + lq * 4 + r;
      // plain dword store: write-through L0 -> lands in this XCD's L2
      __hip_atomic_store(hn + (size_t)row * HID + n0 + l15, w,
                         __ATOMIC_RELAXED, __HIP_MEMORY_SCOPE_WORKGROUP);
    }

    // xproj for NEXT step AFTER publishing: off the store-latency path
    if (t + 1 < T_SEQ)
      xproj(t + 1, xacc);
  }

  // ---- final linear: out = h_512 @ w_lin^T + b_lin (tag 512, buffer 0) ----
  if (ni == 0) {
    const unsigned long long tp = 512ULL | (512ULL << 32);
    float bl = b_lin[0];
    f32x4 w0 = *(const f32x4*)(w_lin + lane * 8);
    f32x4 w1 = *(const f32x4*)(w_lin + lane * 8 + 4);
#pragma unroll 1
    for (int r = 0; r < 4; ++r) {
      int row = m16 + wave * 4 + r;
      const unsigned long long* hp =
          (const unsigned long long*)ws + ((size_t)row * HID + (size_t)lane * 8) / 2;
      unsigned long long q0, q1, q2, q3;
      for (;;) {
        q0 = ald(hp); q1 = ald(hp + 1); q2 = ald(hp + 2); q3 = ald(hp + 3);
        unsigned long long diff = ((q0 ^ tp) | (q1 ^ tp) | (q2 ^ tp) | (q3 ^ tp))
                                  & 0x0000ffff0000ffffULL;
        if (__all(diff == 0)) break;
      }
      float s = 0.f;
      s += bf2f((unsigned short)(q0 >> 16)) * w0[0] + bf2f((unsigned short)(q0 >> 48)) * w0[1];
      s += bf2f((unsigned short)(q1 >> 16)) * w0[2] + bf2f((unsigned short)(q1 >> 48)) * w0[3];
      s += bf2f((unsigned short)(q2 >> 16)) * w1[0] + bf2f((unsigned short)(q2 >> 48)) * w1[1];
      s += bf2f((unsigned short)(q3 >> 16)) * w1[2] + bf2f((unsigned short)(q3 >> 48)) * w1[3];
#pragma unroll
      for (int off = 32; off >= 1; off >>= 1)
        s += __shfl_xor(s, off, 64);
      if (lane == 0) out[row] = s + bl;
    }
  }
}

extern "C" void kernel_launch(void* const* d_in, const int* in_sizes, int n_in,
                              void* d_out, int out_size, void* d_ws, size_t ws_size,
                              hipStream_t stream)
{
  const float* x     = (const float*)d_in[0];
  const float* w_ih  = (const float*)d_in[1];
  const float* w_hh  = (const float*)d_in[2];
  const float* b_ih  = (const float*)d_in[3];
  const float* b_hh  = (const float*)d_in[4];
  const float* w_lin = (const float*)d_in[5];
  const float* b_lin = (const float*)d_in[6];

  // ws: [0,512K) tagged h buf0 | [512K,1M) tagged h buf1 | [1M,+4K) tickets.
  // Memset clears epochs+tickets (replay-safe: stale tags never match 1..512).
  hipMemsetAsync(d_ws, 0, 2 * HBUF + 4096, stream);
  hipLaunchKernelGGL(lstm_persist, dim3(256), dim3(256), 0, stream,
                     x, w_ih, w_hh, b_ih, b_hh, w_lin, b_lin,
                     (float*)d_out, (unsigned char*)d_ws);
}

// Round 12
// 2006.822 us; speedup vs baseline: 4.0796x; 4.0796x over previous
//
#include <hip/hip_runtime.h>
#include <hip/hip_bf16.h>

#define T_SEQ 512
#define HID   512
#define IND   128
#define HBUF  524288          // bytes per tagged h buffer: 256*512*4
#define TICKO (2 * HBUF)      // per-XCD ticket counters

typedef __attribute__((ext_vector_type(8))) short short8;
typedef __attribute__((ext_vector_type(4))) float f32x4;
typedef __attribute__((ext_vector_type(4))) unsigned int uint4v;

static __device__ __forceinline__ unsigned short f2bf(float x) {
  __hip_bfloat16 h = __float2bfloat16(x);
  return __builtin_bit_cast(unsigned short, h);
}
static __device__ __forceinline__ float bf2f(unsigned short s) {
  unsigned u = ((unsigned)s) << 16;
  return __builtin_bit_cast(float, u);
}
static __device__ __forceinline__ float sigf(float x) {
  return 1.0f / (1.0f + __expf(-x));
}
static __device__ __forceinline__ float tanhfast(float x) {
  float e = __expf(2.0f * x);   // saturates cleanly, no inf/inf
  return 1.0f - 2.0f / (e + 1.0f);
}
static __device__ __forceinline__ unsigned long long ald(const unsigned long long* p) {
  return __hip_atomic_load(p, __ATOMIC_RELAXED, __HIP_MEMORY_SCOPE_AGENT);
}

__global__ __launch_bounds__(256, 1)
void lstm_persist(const float* __restrict__ x,
                  const float* __restrict__ w_ih,
                  const float* __restrict__ w_hh,
                  const float* __restrict__ b_ih,
                  const float* __restrict__ b_hh,
                  const float* __restrict__ w_lin,
                  const float* __restrict__ b_lin,
                  float* __restrict__ out,
                  unsigned char* __restrict__ ws)
{
  // LDS 128KB (forces exactly 1 WG/CU -> exactly 32 WGs per XCD):
  // [0,32K) h tile double-buffer (2 x [16][512] bf16, swizzled); doubles as
  //         w_hh staging in the preamble. [64K,128K) w_ih resident.
  __shared__ unsigned char lds[131072];
  __shared__ int slot_sh;

  const int tid  = threadIdx.x;
  const int wave = tid >> 6;
  const int lane = tid & 63;
  const int l15  = lane & 15;
  const int lq   = lane >> 4;

  // ---- runtime XCD-local group formation ----
  unsigned xcd;
  asm volatile("s_getreg_b32 %0, hwreg(HW_REG_XCC_ID)" : "=s"(xcd));
  if (tid == 0) {
    unsigned* tick = (unsigned*)(ws + TICKO) + (size_t)xcd * 32;  // 128B apart
    slot_sh = (int)__hip_atomic_fetch_add(tick, 1u, __ATOMIC_RELAXED,
                                          __HIP_MEMORY_SCOPE_AGENT);
  }
  __syncthreads();
  const int slot = slot_sh;
  if (slot >= 16) return;                 // 16 workers per XCD, rest exit
  const int grp = (int)xcd * 2 + (slot >> 3);   // 0..15, both groups same XCD
  const int ni  = slot & 7;                     // 0..7: WG's 64 h-col slice
  const int m16 = grp * 16;                     // group's batch rows
  const int n0  = ni * 64 + wave * 16;          // this wave's h-col base

  // ---- stage w_ih: 256 gate-rows (4 gates x 64 cols of this WG) x 128 k ----
  for (int it = 0; it < 16; ++it) {
    int idx  = it * 256 + tid;        // 0..4095
    int r    = idx >> 4;              // 0..255
    int c8   = idx & 15;
    int grow = (r >> 6) * HID + ni * 64 + (r & 63);
    const float* gp = w_ih + (size_t)grow * IND + c8 * 8;
    f32x4 a = *(const f32x4*)gp;
    f32x4 b = *(const f32x4*)(gp + 4);
    short8 s;
    s[0] = (short)f2bf(a[0]); s[1] = (short)f2bf(a[1]);
    s[2] = (short)f2bf(a[2]); s[3] = (short)f2bf(a[3]);
    s[4] = (short)f2bf(b[0]); s[5] = (short)f2bf(b[1]);
    s[6] = (short)f2bf(b[2]); s[7] = (short)f2bf(b[3]);
    int off = 65536 + r * 256 + ((c8 * 16) ^ ((r & 7) << 4));
    *(short8*)(lds + off) = s;
  }

  // ---- stage + gather w_hh in 4 rounds (round rd serves wave rd) ----
  short8 wf[64];
  for (int rd = 0; rd < 4; ++rd) {
    __syncthreads();                  // prior round's gather done before overwrite
    for (int it = 0; it < 16; ++it) {
      int idx  = it * 256 + tid;      // 0..4095
      int r    = idx >> 6;            // 0..63  (gate*16 + j)
      int c8   = idx & 63;
      int grow = (r >> 4) * HID + ni * 64 + rd * 16 + (r & 15);
      const float* gp = w_hh + (size_t)grow * HID + c8 * 8;
      f32x4 a = *(const f32x4*)gp;
      f32x4 b = *(const f32x4*)(gp + 4);
      short8 s;
      s[0] = (short)f2bf(a[0]); s[1] = (short)f2bf(a[1]);
      s[2] = (short)f2bf(a[2]); s[3] = (short)f2bf(a[3]);
      s[4] = (short)f2bf(b[0]); s[5] = (short)f2bf(b[1]);
      s[6] = (short)f2bf(b[2]); s[7] = (short)f2bf(b[3]);
      int off = r * 1024 + ((c8 * 16) ^ ((r & 7) << 4));
      *(short8*)(lds + off) = s;
    }
    __syncthreads();
    if (wave == rd) {
      // pin this wave's 64 B-fragments in regs: volatile (cannot rematerialize)
#pragma unroll
      for (int gg = 0; gg < 4; ++gg) {
#pragma unroll
        for (int ks = 0; ks < 16; ++ks) {
          int r   = gg * 16 + l15;
          int off = r * 1024 + (((ks * 64) + lq * 16) ^ ((r & 7) << 4));
          wf[gg * 16 + ks] = *(const volatile short8*)(lds + off);
        }
      }
    }
  }
  __syncthreads();   // protect staging until last gather done

  // bias per gate for this lane's column
  float biasv[4];
#pragma unroll
  for (int gg = 0; gg < 4; ++gg) {
    int gc = gg * HID + n0 + l15;
    biasv[gg] = b_ih[gc] + b_hh[gc];
  }

  // per-lane x base (bytes): row = m16 + l15, chunk lq*8 fp32
  const unsigned char* xbase = (const unsigned char*)x
      + (size_t)(m16 + l15) * T_SEQ * IND * 4 + (size_t)lq * 32;

  f32x4 cacc = {0.f, 0.f, 0.f, 0.f};

  // ---- x-projection (B-frags from LDS; dst = bias + x_t @ w_ih^T) ----
  auto xproj = [&](int t, f32x4* dst) {
    const float* xp = (const float*)(xbase + (size_t)t * IND * 4);
    short8 xa[4];
#pragma unroll
    for (int ks = 0; ks < 4; ++ks) {
      f32x4 a = *(const f32x4*)(xp + ks * 32);
      f32x4 b = *(const f32x4*)(xp + ks * 32 + 4);
      short8 s;
      s[0] = (short)f2bf(a[0]); s[1] = (short)f2bf(a[1]);
      s[2] = (short)f2bf(a[2]); s[3] = (short)f2bf(a[3]);
      s[4] = (short)f2bf(b[0]); s[5] = (short)f2bf(b[1]);
      s[6] = (short)f2bf(b[2]); s[7] = (short)f2bf(b[3]);
      xa[ks] = s;
    }
#pragma unroll
    for (int gg = 0; gg < 4; ++gg) {
      f32x4 v = {biasv[gg], biasv[gg], biasv[gg], biasv[gg]};
      dst[gg] = v;
    }
#pragma unroll
    for (int ks = 0; ks < 4; ++ks) {
#pragma unroll
      for (int gg = 0; gg < 4; ++gg) {
        int rr  = gg * 64 + wave * 16 + l15;
        int off = 65536 + rr * 256 + (((ks * 64) + lq * 16) ^ ((rr & 7) << 4));
        short8 bfr = *(const short8*)(lds + off);
        dst[gg] = __builtin_amdgcn_mfma_f32_16x16x32_bf16(xa[ks], bfr, dst[gg], 0, 0, 0);
      }
    }
  };

  f32x4 xacc[4];
  xproj(0, xacc);

#pragma unroll 1
  for (int t = 0; t < T_SEQ; ++t) {
    short8 ha[16];
    if (t > 0) {
      const int pr = t & 1;
      // dedup by ROWS: this wave bulk-reads rows [wave*4, wave*4+4) x 512 cols
      // via device-scope (sc1) coalesced dwordx4 at stride 256B. sc1 = the SC
      // encoding the compiler emits for agent-scope atomic loads (the path
      // proven to observe same-XCD L2 stores, r6-r11); per-dword tag+value
      // makes dword-granular tearing harmless.
      const int lr = lane >> 4;            // row-in-quartet
      const int lc = lane & 15;            // 16B chunk
      const int tr = wave * 4 + lr;        // tile row 0..15
      const unsigned char* hb = ws + (size_t)pr * HBUF
          + ((size_t)(m16 + tr) * HID + (size_t)lc * 4) * 4;
      const unsigned long long tp =
          (unsigned long long)(unsigned)t | ((unsigned long long)(unsigned)t << 32);
      uint4v q[8];
      for (;;) {
        asm volatile(
          "global_load_dwordx4 %0, %8, off sc1\n\t"
          "global_load_dwordx4 %1, %8, off offset:256 sc1\n\t"
          "global_load_dwordx4 %2, %8, off offset:512 sc1\n\t"
          "global_load_dwordx4 %3, %8, off offset:768 sc1\n\t"
          "global_load_dwordx4 %4, %8, off offset:1024 sc1\n\t"
          "global_load_dwordx4 %5, %8, off offset:1280 sc1\n\t"
          "global_load_dwordx4 %6, %8, off offset:1536 sc1\n\t"
          "global_load_dwordx4 %7, %8, off offset:1792 sc1\n\t"
          "s_waitcnt vmcnt(0)"
          : "=&v"(q[0]), "=&v"(q[1]), "=&v"(q[2]), "=&v"(q[3]),
            "=&v"(q[4]), "=&v"(q[5]), "=&v"(q[6]), "=&v"(q[7])
          : "v"(hb)
          : "memory");
        unsigned long long diff = 0;
#pragma unroll
        for (int j = 0; j < 8; ++j) {
          unsigned long long d0 =
              ((unsigned long long)q[j][1] << 32) | (unsigned long long)q[j][0];
          unsigned long long d1 =
              ((unsigned long long)q[j][3] << 32) | (unsigned long long)q[j][2];
          diff |= ((d0 ^ tp) | (d1 ^ tp)) & 0x0000ffff0000ffffULL;
        }
        if (__all(diff == 0)) break;
      }
      // extract bf16 (high16 of each dword) -> swizzled LDS tile row tr
      unsigned char* hl = lds + (size_t)pr * 16384;
#pragma unroll
      for (int j = 0; j < 8; ++j) {
        unsigned w0 = (q[j][0] >> 16) | (q[j][1] & 0xffff0000u);
        unsigned w1 = (q[j][2] >> 16) | (q[j][3] & 0xffff0000u);
        unsigned long long wv = (unsigned long long)w0 | ((unsigned long long)w1 << 32);
        int off = tr * 1024 + ((lc * 8 + j * 128) ^ ((tr & 7) << 4));
        *(unsigned long long*)(hl + off) = wv;
      }
      __syncthreads();
      // all waves read their A-frags from the LDS tile
#pragma unroll
      for (int ks = 0; ks < 16; ++ks) {
        int off = pr * 16384 + l15 * 1024 + ((ks * 64 + lq * 16) ^ ((l15 & 7) << 4));
        ha[ks] = *(const short8*)(lds + off);
      }
    }

    f32x4 acc[4];
#pragma unroll
    for (int gg = 0; gg < 4; ++gg) acc[gg] = xacc[gg];

    if (t > 0) {
#pragma unroll
      for (int ks = 0; ks < 16; ++ks) {
#pragma unroll
        for (int gg = 0; gg < 4; ++gg)
          acc[gg] = __builtin_amdgcn_mfma_f32_16x16x32_bf16(ha[ks], wf[gg * 16 + ks], acc[gg], 0, 0, 0);
      }
    }

    // ---- pointwise LSTM cell (C/D layout: col=l15, row=lq*4+r) ----
    unsigned* hn = (unsigned*)(ws + (size_t)((t + 1) & 1) * HBUF);
    const unsigned tag = (unsigned)(t + 1);
#pragma unroll
    for (int r = 0; r < 4; ++r) {
      float iv = sigf(acc[0][r]);
      float fv = sigf(acc[1][r]);
      float gv = tanhfast(acc[2][r]);
      float ov = sigf(acc[3][r]);
      float cn = fv * cacc[r] + iv * gv;
      cacc[r] = cn;
      unsigned w = ((unsigned)f2bf(ov * tanhfast(cn)) << 16) | tag;
      int row = m16 + lq * 4 + r;
      // plain dword store: write-through L0 -> lands in this XCD's L2
      __hip_atomic_store(hn + (size_t)row * HID + n0 + l15, w,
                         __ATOMIC_RELAXED, __HIP_MEMORY_SCOPE_WORKGROUP);
    }

    // xproj for NEXT step AFTER publishing: off the store-latency path
    if (t + 1 < T_SEQ)
      xproj(t + 1, xacc);
  }

  // ---- final linear: out = h_512 @ w_lin^T + b_lin (tag 512, buffer 0) ----
  if (ni == 0) {
    const unsigned long long tp = 512ULL | (512ULL << 32);
    float bl = b_lin[0];
    f32x4 w0 = *(const f32x4*)(w_lin + lane * 8);
    f32x4 w1 = *(const f32x4*)(w_lin + lane * 8 + 4);
#pragma unroll 1
    for (int r = 0; r < 4; ++r) {
      int row = m16 + wave * 4 + r;
      const unsigned long long* hp =
          (const unsigned long long*)ws + ((size_t)row * HID + (size_t)lane * 8) / 2;
      unsigned long long q0, q1, q2, q3;
      for (;;) {
        q0 = ald(hp); q1 = ald(hp + 1); q2 = ald(hp + 2); q3 = ald(hp + 3);
        unsigned long long diff = ((q0 ^ tp) | (q1 ^ tp) | (q2 ^ tp) | (q3 ^ tp))
                                  & 0x0000ffff0000ffffULL;
        if (__all(diff == 0)) break;
      }
      float s = 0.f;
      s += bf2f((unsigned short)(q0 >> 16)) * w0[0] + bf2f((unsigned short)(q0 >> 48)) * w0[1];
      s += bf2f((unsigned short)(q1 >> 16)) * w0[2] + bf2f((unsigned short)(q1 >> 48)) * w0[3];
      s += bf2f((unsigned short)(q2 >> 16)) * w1[0] + bf2f((unsigned short)(q2 >> 48)) * w1[1];
      s += bf2f((unsigned short)(q3 >> 16)) * w1[2] + bf2f((unsigned short)(q3 >> 48)) * w1[3];
#pragma unroll
      for (int off = 32; off >= 1; off >>= 1)
        s += __shfl_xor(s, off, 64);
      if (lane == 0) out[row] = s + bl;
    }
  }
}

extern "C" void kernel_launch(void* const* d_in, const int* in_sizes, int n_in,
                              void* d_out, int out_size, void* d_ws, size_t ws_size,
                              hipStream_t stream)
{
  const float* x     = (const float*)d_in[0];
  const float* w_ih  = (const float*)d_in[1];
  const float* w_hh  = (const float*)d_in[2];
  const float* b_ih  = (const float*)d_in[3];
  const float* b_hh  = (const float*)d_in[4];
  const float* w_lin = (const float*)d_in[5];
  const float* b_lin = (const float*)d_in[6];

  // ws: [0,512K) tagged h buf0 | [512K,1M) tagged h buf1 | [1M,+4K) tickets.
  // Memset clears epochs+tickets (replay-safe: stale tags never match 1..512).
  hipMemsetAsync(d_ws, 0, 2 * HBUF + 4096, stream);
  hipLaunchKernelGGL(lstm_persist, dim3(256), dim3(256), 0, stream,
                     x, w_ih, w_hh, b_ih, b_hh, w_lin, b_lin,
                     (float*)d_out, (unsigned char*)d_ws);
}

// Round 13
// 1612.345 us; speedup vs baseline: 5.0778x; 1.2447x over previous
//
#include <hip/hip_runtime.h>
#include <hip/hip_bf16.h>

#define T_SEQ 512
#define HID   512
#define IND   128
#define HBUF  524288          // bytes per tagged h buffer: 256*512*4
#define TICKO (2 * HBUF)      // per-XCD ticket counters

typedef __attribute__((ext_vector_type(8))) short short8;
typedef __attribute__((ext_vector_type(4))) float f32x4;
typedef __attribute__((ext_vector_type(4))) unsigned int uint4v;

static __device__ __forceinline__ unsigned short f2bf(float x) {
  __hip_bfloat16 h = __float2bfloat16(x);
  return __builtin_bit_cast(unsigned short, h);
}
static __device__ __forceinline__ float bf2f(unsigned short s) {
  unsigned u = ((unsigned)s) << 16;
  return __builtin_bit_cast(float, u);
}
static __device__ __forceinline__ float sigf(float x) {
  // single v_rcp (no Newton refine): ~1e-6 rel err, invisible under bf16
  return __builtin_amdgcn_rcpf(1.0f + __expf(-x));
}
static __device__ __forceinline__ float tanhfast(float x) {
  // 1 - 2/(e^{2x}+1): saturates cleanly (rcp(inf)=0)
  return 1.0f - 2.0f * __builtin_amdgcn_rcpf(__expf(2.0f * x) + 1.0f);
}
static __device__ __forceinline__ unsigned long long ald(const unsigned long long* p) {
  return __hip_atomic_load(p, __ATOMIC_RELAXED, __HIP_MEMORY_SCOPE_AGENT);
}

__global__ __launch_bounds__(256, 1)
void lstm_persist(const float* __restrict__ x,
                  const float* __restrict__ w_ih,
                  const float* __restrict__ w_hh,
                  const float* __restrict__ b_ih,
                  const float* __restrict__ b_hh,
                  const float* __restrict__ w_lin,
                  const float* __restrict__ b_lin,
                  float* __restrict__ out,
                  unsigned char* __restrict__ ws)
{
  // LDS 128KB (forces exactly 1 WG/CU -> exactly 32 WGs per XCD):
  // [0,32K) h tile double-buffer (2 x [16][512] bf16, swizzled); doubles as
  //         w_hh staging in the preamble. [64K,128K) w_ih resident.
  __shared__ unsigned char lds[131072];
  __shared__ int slot_sh;

  const int tid  = threadIdx.x;
  const int wave = tid >> 6;
  const int lane = tid & 63;
  const int l15  = lane & 15;
  const int lq   = lane >> 4;

  // ---- runtime XCD-local group formation ----
  unsigned xcd;
  asm volatile("s_getreg_b32 %0, hwreg(HW_REG_XCC_ID)" : "=s"(xcd));
  if (tid == 0) {
    unsigned* tick = (unsigned*)(ws + TICKO) + (size_t)xcd * 32;  // 128B apart
    slot_sh = (int)__hip_atomic_fetch_add(tick, 1u, __ATOMIC_RELAXED,
                                          __HIP_MEMORY_SCOPE_AGENT);
  }
  __syncthreads();
  const int slot = slot_sh;
  if (slot >= 16) return;                 // 16 workers per XCD, rest exit
  const int grp = (int)xcd * 2 + (slot >> 3);   // 0..15, both groups same XCD
  const int ni  = slot & 7;                     // 0..7: WG's 64 h-col slice
  const int m16 = grp * 16;                     // group's batch rows
  const int n0  = ni * 64 + wave * 16;          // this wave's h-col base

  // ---- stage w_ih: 256 gate-rows (4 gates x 64 cols of this WG) x 128 k ----
  for (int it = 0; it < 16; ++it) {
    int idx  = it * 256 + tid;        // 0..4095
    int r    = idx >> 4;              // 0..255
    int c8   = idx & 15;
    int grow = (r >> 6) * HID + ni * 64 + (r & 63);
    const float* gp = w_ih + (size_t)grow * IND + c8 * 8;
    f32x4 a = *(const f32x4*)gp;
    f32x4 b = *(const f32x4*)(gp + 4);
    short8 s;
    s[0] = (short)f2bf(a[0]); s[1] = (short)f2bf(a[1]);
    s[2] = (short)f2bf(a[2]); s[3] = (short)f2bf(a[3]);
    s[4] = (short)f2bf(b[0]); s[5] = (short)f2bf(b[1]);
    s[6] = (short)f2bf(b[2]); s[7] = (short)f2bf(b[3]);
    int off = 65536 + r * 256 + ((c8 * 16) ^ ((r & 7) << 4));
    *(short8*)(lds + off) = s;
  }

  // ---- stage + gather w_hh in 4 rounds (round rd serves wave rd) ----
  short8 wf[64];
  for (int rd = 0; rd < 4; ++rd) {
    __syncthreads();                  // prior round's gather done before overwrite
    for (int it = 0; it < 16; ++it) {
      int idx  = it * 256 + tid;      // 0..4095
      int r    = idx >> 6;            // 0..63  (gate*16 + j)
      int c8   = idx & 63;
      int grow = (r >> 4) * HID + ni * 64 + rd * 16 + (r & 15);
      const float* gp = w_hh + (size_t)grow * HID + c8 * 8;
      f32x4 a = *(const f32x4*)gp;
      f32x4 b = *(const f32x4*)(gp + 4);
      short8 s;
      s[0] = (short)f2bf(a[0]); s[1] = (short)f2bf(a[1]);
      s[2] = (short)f2bf(a[2]); s[3] = (short)f2bf(a[3]);
      s[4] = (short)f2bf(b[0]); s[5] = (short)f2bf(b[1]);
      s[6] = (short)f2bf(b[2]); s[7] = (short)f2bf(b[3]);
      int off = r * 1024 + ((c8 * 16) ^ ((r & 7) << 4));
      *(short8*)(lds + off) = s;
    }
    __syncthreads();
    if (wave == rd) {
      // pin this wave's 64 B-fragments in regs: volatile (cannot rematerialize)
#pragma unroll
      for (int gg = 0; gg < 4; ++gg) {
#pragma unroll
        for (int ks = 0; ks < 16; ++ks) {
          int r   = gg * 16 + l15;
          int off = r * 1024 + (((ks * 64) + lq * 16) ^ ((r & 7) << 4));
          wf[gg * 16 + ks] = *(const volatile short8*)(lds + off);
        }
      }
    }
  }
  __syncthreads();   // protect staging until last gather done

  // bias per gate for this lane's column
  float biasv[4];
#pragma unroll
  for (int gg = 0; gg < 4; ++gg) {
    int gc = gg * HID + n0 + l15;
    biasv[gg] = b_ih[gc] + b_hh[gc];
  }

  // per-lane x base (bytes): row = m16 + l15, chunk lq*8 fp32
  const unsigned char* xbase = (const unsigned char*)x
      + (size_t)(m16 + l15) * T_SEQ * IND * 4 + (size_t)lq * 32;

  f32x4 cacc = {0.f, 0.f, 0.f, 0.f};

  // ---- x load (issued early; latency hidden under the h poll) ----
  auto xload = [&](int t, f32x4* xr) {
    const float* xp = (const float*)(xbase + (size_t)t * IND * 4);
#pragma unroll
    for (int ks = 0; ks < 4; ++ks) {
      xr[ks * 2]     = *(const f32x4*)(xp + ks * 32);
      xr[ks * 2 + 1] = *(const f32x4*)(xp + ks * 32 + 4);
    }
  };
  // ---- x-projection from preloaded registers (B-frags from LDS) ----
  auto xproj = [&](const f32x4* xr, f32x4* dst) {
    short8 xa[4];
#pragma unroll
    for (int ks = 0; ks < 4; ++ks) {
      f32x4 a = xr[ks * 2];
      f32x4 b = xr[ks * 2 + 1];
      short8 s;
      s[0] = (short)f2bf(a[0]); s[1] = (short)f2bf(a[1]);
      s[2] = (short)f2bf(a[2]); s[3] = (short)f2bf(a[3]);
      s[4] = (short)f2bf(b[0]); s[5] = (short)f2bf(b[1]);
      s[6] = (short)f2bf(b[2]); s[7] = (short)f2bf(b[3]);
      xa[ks] = s;
    }
#pragma unroll
    for (int gg = 0; gg < 4; ++gg) {
      f32x4 v = {biasv[gg], biasv[gg], biasv[gg], biasv[gg]};
      dst[gg] = v;
    }
#pragma unroll
    for (int ks = 0; ks < 4; ++ks) {
#pragma unroll
      for (int gg = 0; gg < 4; ++gg) {
        int rr  = gg * 64 + wave * 16 + l15;
        int off = 65536 + rr * 256 + (((ks * 64) + lq * 16) ^ ((rr & 7) << 4));
        short8 bfr = *(const short8*)(lds + off);
        dst[gg] = __builtin_amdgcn_mfma_f32_16x16x32_bf16(xa[ks], bfr, dst[gg], 0, 0, 0);
      }
    }
  };

  f32x4 xr[8];
  f32x4 xacc[4];
  xload(0, xr);
  xproj(xr, xacc);

#pragma unroll 1
  for (int t = 0; t < T_SEQ; ++t) {
    // issue x loads for t+1 NOW: they complete under the h poll below
    {
      int tn = (t + 1 < T_SEQ) ? t + 1 : T_SEQ - 1;
      xload(tn, xr);
    }

    short8 ha[16];
    if (t > 0) {
      const int pr = t & 1;
      // dedup by ROWS: this wave bulk-reads rows [wave*4, wave*4+4) x 512 cols
      // via device-scope (sc1) coalesced dwordx4 at stride 256B.
      const int lr = lane >> 4;            // row-in-quartet
      const int lc = lane & 15;            // 16B chunk
      const int tr = wave * 4 + lr;        // tile row 0..15
      const unsigned char* hb = ws + (size_t)pr * HBUF
          + ((size_t)(m16 + tr) * HID + (size_t)lc * 4) * 4;
      const unsigned long long tp =
          (unsigned long long)(unsigned)t | ((unsigned long long)(unsigned)t << 32);
      uint4v q[8];
      for (;;) {
        asm volatile(
          "global_load_dwordx4 %0, %8, off sc1\n\t"
          "global_load_dwordx4 %1, %8, off offset:256 sc1\n\t"
          "global_load_dwordx4 %2, %8, off offset:512 sc1\n\t"
          "global_load_dwordx4 %3, %8, off offset:768 sc1\n\t"
          "global_load_dwordx4 %4, %8, off offset:1024 sc1\n\t"
          "global_load_dwordx4 %5, %8, off offset:1280 sc1\n\t"
          "global_load_dwordx4 %6, %8, off offset:1536 sc1\n\t"
          "global_load_dwordx4 %7, %8, off offset:1792 sc1\n\t"
          "s_waitcnt vmcnt(0)"
          : "=&v"(q[0]), "=&v"(q[1]), "=&v"(q[2]), "=&v"(q[3]),
            "=&v"(q[4]), "=&v"(q[5]), "=&v"(q[6]), "=&v"(q[7])
          : "v"(hb)
          : "memory");
        unsigned long long diff = 0;
#pragma unroll
        for (int j = 0; j < 8; ++j) {
          unsigned long long d0 =
              ((unsigned long long)q[j][1] << 32) | (unsigned long long)q[j][0];
          unsigned long long d1 =
              ((unsigned long long)q[j][3] << 32) | (unsigned long long)q[j][2];
          diff |= ((d0 ^ tp) | (d1 ^ tp)) & 0x0000ffff0000ffffULL;
        }
        if (__all(diff == 0)) break;
      }
      // extract bf16 (high16 of each dword) -> swizzled LDS tile row tr
      unsigned char* hl = lds + (size_t)pr * 16384;
#pragma unroll
      for (int j = 0; j < 8; ++j) {
        unsigned w0 = (q[j][0] >> 16) | (q[j][1] & 0xffff0000u);
        unsigned w1 = (q[j][2] >> 16) | (q[j][3] & 0xffff0000u);
        unsigned long long wv = (unsigned long long)w0 | ((unsigned long long)w1 << 32);
        int off = tr * 1024 + ((lc * 8 + j * 128) ^ ((tr & 7) << 4));
        *(unsigned long long*)(hl + off) = wv;
      }
      __syncthreads();
      // all waves read their A-frags from the LDS tile
#pragma unroll
      for (int ks = 0; ks < 16; ++ks) {
        int off = pr * 16384 + l15 * 1024 + ((ks * 64 + lq * 16) ^ ((l15 & 7) << 4));
        ha[ks] = *(const short8*)(lds + off);
      }
    }

    f32x4 acc[4];
#pragma unroll
    for (int gg = 0; gg < 4; ++gg) acc[gg] = xacc[gg];

    if (t > 0) {
#pragma unroll
      for (int ks = 0; ks < 16; ++ks) {
#pragma unroll
        for (int gg = 0; gg < 4; ++gg)
          acc[gg] = __builtin_amdgcn_mfma_f32_16x16x32_bf16(ha[ks], wf[gg * 16 + ks], acc[gg], 0, 0, 0);
      }
    }

    // ---- pointwise LSTM cell (C/D layout: col=l15, row=lq*4+r) ----
    unsigned* hn = (unsigned*)(ws + (size_t)((t + 1) & 1) * HBUF);
    const unsigned tag = (unsigned)(t + 1);
#pragma unroll
    for (int r = 0; r < 4; ++r) {
      float iv = sigf(acc[0][r]);
      float fv = sigf(acc[1][r]);
      float gv = tanhfast(acc[2][r]);
      float ov = sigf(acc[3][r]);
      float cn = fv * cacc[r] + iv * gv;
      cacc[r] = cn;
      unsigned w = ((unsigned)f2bf(ov * tanhfast(cn)) << 16) | tag;
      int row = m16 + lq * 4 + r;
      // plain dword store: write-through L0 -> lands in this XCD's L2
      __hip_atomic_store(hn + (size_t)row * HID + n0 + l15, w,
                         __ATOMIC_RELAXED, __HIP_MEMORY_SCOPE_WORKGROUP);
    }

    // xproj for NEXT step AFTER publishing (x data already in registers)
    if (t + 1 < T_SEQ)
      xproj(xr, xacc);
  }

  // ---- final linear: out = h_512 @ w_lin^T + b_lin (tag 512, buffer 0) ----
  if (ni == 0) {
    const unsigned long long tp = 512ULL | (512ULL << 32);
    float bl = b_lin[0];
    f32x4 w0 = *(const f32x4*)(w_lin + lane * 8);
    f32x4 w1 = *(const f32x4*)(w_lin + lane * 8 + 4);
#pragma unroll 1
    for (int r = 0; r < 4; ++r) {
      int row = m16 + wave * 4 + r;
      const unsigned long long* hp =
          (const unsigned long long*)ws + ((size_t)row * HID + (size_t)lane * 8) / 2;
      unsigned long long q0, q1, q2, q3;
      for (;;) {
        q0 = ald(hp); q1 = ald(hp + 1); q2 = ald(hp + 2); q3 = ald(hp + 3);
        unsigned long long diff = ((q0 ^ tp) | (q1 ^ tp) | (q2 ^ tp) | (q3 ^ tp))
                                  & 0x0000ffff0000ffffULL;
        if (__all(diff == 0)) break;
      }
      float s = 0.f;
      s += bf2f((unsigned short)(q0 >> 16)) * w0[0] + bf2f((unsigned short)(q0 >> 48)) * w0[1];
      s += bf2f((unsigned short)(q1 >> 16)) * w0[2] + bf2f((unsigned short)(q1 >> 48)) * w0[3];
      s += bf2f((unsigned short)(q2 >> 16)) * w1[0] + bf2f((unsigned short)(q2 >> 48)) * w1[1];
      s += bf2f((unsigned short)(q3 >> 16)) * w1[2] + bf2f((unsigned short)(q3 >> 48)) * w1[3];
#pragma unroll
      for (int off = 32; off >= 1; off >>= 1)
        s += __shfl_xor(s, off, 64);
      if (lane == 0) out[row] = s + bl;
    }
  }
}

extern "C" void kernel_launch(void* const* d_in, const int* in_sizes, int n_in,
                              void* d_out, int out_size, void* d_ws, size_t ws_size,
                              hipStream_t stream)
{
  const float* x     = (const float*)d_in[0];
  const float* w_ih  = (const float*)d_in[1];
  const float* w_hh  = (const float*)d_in[2];
  const float* b_ih  = (const float*)d_in[3];
  const float* b_hh  = (const float*)d_in[4];
  const float* w_lin = (const float*)d_in[5];
  const float* b_lin = (const float*)d_in[6];

  // ws: [0,512K) tagged h buf0 | [512K,1M) tagged h buf1 | [1M,+4K) tickets.
  // Memset clears epochs+tickets (replay-safe: stale tags never match 1..512).
  hipMemsetAsync(d_ws, 0, 2 * HBUF + 4096, stream);
  hipLaunchKernelGGL(lstm_persist, dim3(256), dim3(256), 0, stream,
                     x, w_ih, w_hh, b_ih, b_hh, w_lin, b_lin,
                     (float*)d_out, (unsigned char*)d_ws);
}